// Round 1
// baseline (5845.202 us; speedup 1.0000x reference)
//
#include <hip/hip_runtime.h>

#define S_TOT 829
#define SP 498
#define BATCH 16
#define NK 200
#define RH 100
#define DMODEL 200
#define G4 400
#define MROWS (BATCH*S_TOT)   // 13264

using v8s = __attribute__((ext_vector_type(8))) short;
using v4f = __attribute__((ext_vector_type(4))) float;

__device__ inline v4f mfma16(v8s a, v8s b, v4f c){
    return __builtin_amdgcn_mfma_f32_16x16x32_bf16(a, b, c, 0, 0, 0);
}
__device__ inline unsigned short f2bf(float f){
    unsigned int u = __float_as_uint(f);
    unsigned int r = (u + 0x7FFFu + ((u >> 16) & 1u)) >> 16;
    return (unsigned short)r;
}
__device__ inline float sigf(float x){ return 1.0f/(1.0f + exp2f(-1.44269504f*x)); }
__device__ inline float tanhfast(float x){ return 2.0f/(1.0f + exp2f(-2.88539008f*x)) - 1.0f; }

// ---------------- prep: weight conversions / transposes ----------------
// WhhBf is stored GATE-PERMUTED: output row p = 16*nt + lc holds gate (lc&3)
// of hidden unit n = 4*nt + (lc>>2).  This makes all 4 gates of a unit land in
// 4 adjacent lanes of one MFMA output tile -> activation via shfl, no LDS trip.
__global__ void prep(const float* __restrict__ w_ih, const float* __restrict__ w_hh,
                     const float* __restrict__ b_ih, const float* __restrict__ b_hh,
                     const float* __restrict__ wq, const float* __restrict__ bq,
                     const float* __restrict__ wk, const float* __restrict__ bk,
                     const float* __restrict__ wv, const float* __restrict__ bv,
                     const float* __restrict__ mh_w,
                     unsigned short* __restrict__ WihBf, float* __restrict__ bias2,
                     unsigned short* __restrict__ WhhBf, unsigned short* __restrict__ wqkvT,
                     float* __restrict__ qkvBias, unsigned short* __restrict__ mhwT)
{
    int t = blockIdx.x*blockDim.x + threadIdx.x;
    if (t < 320000) { WihBf[t] = f2bf(w_ih[t]); }
    else if (t < 323200) { int i = t-320000; bias2[i] = b_ih[i] + b_hh[i]; }
    else if (t < 483200) { int i = t-323200;
        int blk = i/40000, rem = i%40000;
        int p = rem/100, k = rem%100;
        int nt = p>>4, lcp = p&15;
        int n = 4*nt + (lcp>>2), g = lcp&3;
        WhhBf[i] = f2bf(w_hh[blk*40000 + (g*100+n)*100 + k]); }
    else if (t < 636800) { int i = t-483200; int r = i/200, d = i%200;
        int which = r>>8, hh = (r>>5)&7, j = r&31;
        const float* ws = which==0?wq:(which==1?wk:wv);
        wqkvT[i] = f2bf(ws[(hh*200 + d)*32 + j]); }
    else if (t < 637568) { int r = t-636800; int which = r>>8, hh=(r>>5)&7, j=r&31;
        const float* bs = which==0?bq:(which==1?bk:bv);
        qkvBias[r] = bs[hh*32 + j]; }
    else if (t < 663168) { int i = t-637568; int n = i/256, k = i%256;
        mhwT[i] = f2bf(mh_w[k*100 + n]); }
}

// ---------------- conv + BN + ReLU + maxpool(6), writes X bf16 [B,S,200] ----------------
__global__ void conv_pool(const float* __restrict__ xp, const float* __restrict__ xe,
    const float* __restrict__ wp, const float* __restrict__ gp, const float* __restrict__ bp,
    const float* __restrict__ mp, const float* __restrict__ vp,
    const float* __restrict__ we, const float* __restrict__ ge, const float* __restrict__ be,
    const float* __restrict__ me, const float* __restrict__ ve,
    unsigned short* __restrict__ Xbf)
{
    int t = blockIdx.x*blockDim.x + threadIdx.x;
    if (t >= BATCH*S_TOT*NK) return;
    int oc = t % NK;
    int s  = (t / NK) % S_TOT;
    int b  = t / (NK*S_TOT);
    const float *x, *w, *g, *bb, *mm, *vv; int L, sl;
    if (s < SP){ x=xp; w=wp; g=gp; bb=bp; mm=mp; vv=vp; L=3000; sl=s; }
    else       { x=xe; w=we; g=ge; bb=be; mm=me; vv=ve; L=2000; sl=s-SP; }
    float inv = g[oc] * rsqrtf(vv[oc] + 1e-5f);
    float sh  = bb[oc] - mm[oc]*inv;
    int l0 = sl*6;
    const float* xb = x + (long)b*4*L;
    const float* wo = w + oc*52;
    float best = -1e30f;
    for (int u=0; u<6; ++u){
        float a = 0.f;
        #pragma unroll
        for (int ic=0; ic<4; ++ic){
            const float* xr = xb + ic*L + l0 + u;
            const float* wr = wo + ic*13;
            #pragma unroll
            for (int k=0; k<13; ++k) a += xr[k]*wr[k];
        }
        best = fmaxf(best, a*inv + sh);
    }
    Xbf[t] = f2bf(fmaxf(best, 0.f));
}

// ---------------- generic bf16 MFMA GEMM: C[z] = A @ B[z]^T (+bias, relu) ----------------
__global__ __launch_bounds__(256) void gemm_bf16(
    const unsigned short* __restrict__ A, const unsigned short* __restrict__ B,
    const float* __restrict__ bias, float* __restrict__ C, unsigned short* __restrict__ Cbf,
    int M, int N, int K, long strideB, long strideBias, long strideC, int relu)
{
    __shared__ unsigned short As[64][40];
    __shared__ unsigned short Bs[64][40];
    int tid = threadIdx.x;
    int m0 = blockIdx.x*64, n0 = blockIdx.y*64, z = blockIdx.z;
    const unsigned short* Bz = B + z*strideB;
    const float* biasz = bias + z*strideBias;
    float* Cz = C + z*strideC;
    unsigned short* Cbz = Cbf ? Cbf + z*strideC : nullptr;

    int lane = tid & 63, wave = tid >> 6;
    int wm = wave >> 1, wn = wave & 1;
    int quad = lane >> 4, lc = lane & 15;
    int row = tid >> 2, seg = tid & 3;

    v4f acc[2][2];
    #pragma unroll
    for (int i=0;i<2;++i)
      #pragma unroll
      for (int j=0;j<2;++j) acc[i][j] = (v4f){0.f,0.f,0.f,0.f};

    int KC = (K + 31) >> 5;
    for (int kc = 0; kc < KC; ++kc){
        int k0 = kc << 5;
        __syncthreads();
        {
            int gm = m0 + row, gn = n0 + row, ks = k0 + seg*8;
            if (gm < M && ks + 8 <= K)
                *(v8s*)&As[row][seg*8] = *(const v8s*)(A + (long)gm*K + ks);
            else
                for (int j=0;j<8;++j) As[row][seg*8+j] = (gm<M && ks+j<K) ? A[(long)gm*K+ks+j] : 0;
            if (gn < N && ks + 8 <= K)
                *(v8s*)&Bs[row][seg*8] = *(const v8s*)(Bz + (long)gn*K + ks);
            else
                for (int j=0;j<8;++j) Bs[row][seg*8+j] = (gn<N && ks+j<K) ? Bz[(long)gn*K+ks+j] : 0;
        }
        __syncthreads();
        v8s a0 = *(const v8s*)&As[wm*32 + lc][quad*8];
        v8s a1 = *(const v8s*)&As[wm*32 + 16 + lc][quad*8];
        v8s b0 = *(const v8s*)&Bs[wn*32 + lc][quad*8];
        v8s b1 = *(const v8s*)&Bs[wn*32 + 16 + lc][quad*8];
        acc[0][0] = mfma16(a0, b0, acc[0][0]);
        acc[0][1] = mfma16(a0, b1, acc[0][1]);
        acc[1][0] = mfma16(a1, b0, acc[1][0]);
        acc[1][1] = mfma16(a1, b1, acc[1][1]);
    }
    #pragma unroll
    for (int i=0;i<2;++i)
      #pragma unroll
      for (int j=0;j<2;++j){
        int nc = n0 + wn*32 + j*16 + lc;
        #pragma unroll
        for (int r=0;r<4;++r){
            int mr = m0 + wm*32 + i*16 + quad*4 + r;
            if (mr < M && nc < N){
                float v = acc[i][j][r] + biasz[nc];
                if (relu) v = fmaxf(v, 0.f);
                Cz[(long)mr*N + nc] = v;
                if (Cbz) Cbz[(long)mr*N + nc] = f2bf(v);
            }
        }
      }
}

// ---------------- persistent LSTM scan: 1 block per (dir, 2-batch group) ----------------
// One barrier per step (ping-pong h buffers), gate-permuted W_hh so activation
// happens in the producing wave via shfl_xor, gx prefetched 2 steps ahead in
// registers, raw s_barrier with lgkmcnt-only drain so prefetch/stores stay in
// flight across the barrier.
__global__ __launch_bounds__(512) void lstm_scan(
    const float* __restrict__ gx, const unsigned short* __restrict__ whh,
    unsigned short* __restrict__ Hout)
{
    __shared__ unsigned short h_bf[2][16][136];  // ping-pong bf16 h, k-padded
    int tid = threadIdx.x;
    int dir = blockIdx.x >> 3, bg = blockIdx.x & 7;
    int b0 = bg*2;
    int lane = tid & 63, wave = tid >> 6;
    int quad = lane >> 4, lc = lane & 15;
    int m = lc >> 2, r = lc & 3;
    bool actlane = (quad == 0) && (r < 2);

    for (int idx = tid; idx < 2*16*136; idx += 512) ((unsigned short*)h_bf)[idx] = 0;

    // register-resident W_hh B-fragments: wave w owns n-tiles {w, w+8, w+16, w+24} (<25)
    const unsigned short* W = whh + dir*G4*RH;
    v8s bfr[4][4];
    #pragma unroll
    for (int i=0;i<4;++i){
        int nt = wave + 8*i;
        #pragma unroll
        for (int kc=0;kc<4;++kc){
            v8s v;
            #pragma unroll
            for (int j=0;j<8;++j){
                int n = nt*16 + lc, k = kc*32 + quad*8 + j;
                v[j] = (nt<25 && k<RH) ? (short)W[n*RH + k] : (short)0;
            }
            bfr[i][kc] = v;
        }
    }

    // per-tile gx base: this lane handles (batch b0+r, unit n=4*nt+m)
    long rowbase[4];
    #pragma unroll
    for (int i=0;i<4;++i){
        int nt = wave + 8*i;
        rowbase[i] = (((long)dir*BATCH + (b0+r))*S_TOT)*(long)G4 + (4*nt + m);
    }

    float creg[4] = {0.f,0.f,0.f,0.f};
    float gA[4][4], gB[4][4];

    auto loadg = [&](float (&g)[4][4], int t){
        if (t < S_TOT && actlane){
            int s = dir ? (S_TOT-1-t) : t;
            #pragma unroll
            for (int i=0;i<4;++i){
                if (wave + 8*i < 25){
                    const float* gp = gx + rowbase[i] + (long)s*G4;
                    g[i][0]=gp[0]; g[i][1]=gp[100]; g[i][2]=gp[200]; g[i][3]=gp[300];
                }
            }
        }
    };
    loadg(gA, 0);
    loadg(gB, 1);
    __syncthreads();

    auto step = [&](int t, float (&g)[4][4]){
        int pp = t & 1;
        int s = dir ? (S_TOT-1-t) : t;
        v8s afr[4];
        #pragma unroll
        for (int kc=0;kc<4;++kc)
            afr[kc] = *(const v8s*)&h_bf[pp][lc][kc*32 + quad*8];
        #pragma unroll
        for (int i=0;i<4;++i){
            int nt = wave + 8*i;
            if (nt < 25){   // wave-uniform branch
                v4f d0 = (v4f){0.f,0.f,0.f,0.f}, d1 = (v4f){0.f,0.f,0.f,0.f};
                d0 = mfma16(afr[0], bfr[i][0], d0);
                d1 = mfma16(afr[2], bfr[i][2], d1);
                d0 = mfma16(afr[1], bfr[i][1], d0);
                d1 = mfma16(afr[3], bfr[i][3], d1);
                float e0 = d0[0] + d1[0];   // batch b0+0, col 16*nt+lc
                float e1 = d0[1] + d1[1];   // batch b0+1
                // gather all 4 gates of unit 4*nt+m into lanes r=0 (b0) / r=1 (b1)
                float p1v = __shfl_xor(e0,1), p2v = __shfl_xor(e0,2), p3v = __shfl_xor(e0,3);
                float q1v = __shfl_xor(e1,1), q2v = __shfl_xor(e1,2), q3v = __shfl_xor(e1,3);
                float gi, gf, gg, go;
                if (r == 0){ gi = e0;  gf = p1v; gg = p2v; go = p3v; }
                else       { gi = q1v; gf = e1;  gg = q3v; go = q2v; }
                if (actlane){
                    gi += g[i][0]; gf += g[i][1]; gg += g[i][2]; go += g[i][3];
                    creg[i] = sigf(gf)*creg[i] + sigf(gi)*tanhfast(gg);
                    float hv = sigf(go)*tanhfast(creg[i]);
                    unsigned short hb = f2bf(hv);
                    int n = 4*nt + m;
                    h_bf[pp^1][r][n] = hb;
                    Hout[((long)(b0+r)*S_TOT + s)*DMODEL + dir*RH + n] = hb;
                }
            }
        }
        loadg(g, t+2);   // prefetch 2 steps ahead into the buffer just consumed
        // drain LDS writes only; leave prefetch loads + Hout stores in flight
        asm volatile("s_waitcnt lgkmcnt(0)" ::: "memory");
        __builtin_amdgcn_s_barrier();
    };

    for (int t=0; t+1 < S_TOT; t += 2){
        step(t,   gA);
        step(t+1, gB);
    }
    step(S_TOT-1, gA);   // S_TOT odd: final (even) step consumes gA
}

// ---------------- fused scores + softmax + PV, per (b,h,s-tile of 16) ----------------
__global__ __launch_bounds__(256) void attn_fused(
    const unsigned short* __restrict__ qkvbf, const float* __restrict__ qkvf,
    float* __restrict__ outP, unsigned short* __restrict__ attn_cat)
{
    __shared__ unsigned short P_lds[16][840];
    __shared__ float redbuf[4][16];
    __shared__ float attnbuf[4][16][17];
    int tid = threadIdx.x;
    int lane = tid & 63, wave = tid >> 6;
    int quad = lane >> 4, lc = lane & 15;
    int b = blockIdx.y >> 3, h = blockIdx.y & 7;
    int s0 = blockIdx.x*16;
    const float scale = 0.17677669529663687f;

    v8s aq = (v8s){0,0,0,0,0,0,0,0};
    int sg = s0 + lc;
    if (sg < S_TOT) aq = *(const v8s*)(qkvbf + ((long)(b*S_TOT + sg))*768 + h*32 + quad*8);

    v4f frag[13];
    #pragma unroll
    for (int i=0;i<13;++i){
        int tg = (i*4 + wave)*16 + lc;
        v8s bk = (v8s){0,0,0,0,0,0,0,0};
        if (tg < S_TOT) bk = *(const v8s*)(qkvbf + ((long)(b*S_TOT + tg))*768 + 256 + h*32 + quad*8);
        v4f z = (v4f){0.f,0.f,0.f,0.f};
        frag[i] = mfma16(aq, bk, z);
    }
    float mx[4] = {-1e30f,-1e30f,-1e30f,-1e30f};
    #pragma unroll
    for (int i=0;i<13;++i){
        int tcol = (i*4+wave)*16 + lc;
        bool tv = tcol < S_TOT;
        #pragma unroll
        for (int r=0;r<4;++r){
            float x = tv ? frag[i][r]*scale : -1e30f;
            frag[i][r] = x;
            mx[r] = fmaxf(mx[r], x);
        }
    }
    #pragma unroll
    for (int off=1; off<16; off<<=1)
        #pragma unroll
        for (int r=0;r<4;++r) mx[r] = fmaxf(mx[r], __shfl_xor(mx[r], off));
    if (lc == 0){ redbuf[wave][quad*4+0]=mx[0]; redbuf[wave][quad*4+1]=mx[1];
                  redbuf[wave][quad*4+2]=mx[2]; redbuf[wave][quad*4+3]=mx[3]; }
    __syncthreads();
    float M4[4], sm[4] = {0.f,0.f,0.f,0.f};
    #pragma unroll
    for (int r=0;r<4;++r){
        int rr = quad*4+r;
        M4[r] = fmaxf(fmaxf(redbuf[0][rr], redbuf[1][rr]), fmaxf(redbuf[2][rr], redbuf[3][rr]));
    }
    #pragma unroll
    for (int i=0;i<13;++i)
        #pragma unroll
        for (int r=0;r<4;++r){
            float e = exp2f((frag[i][r] - M4[r]) * 1.44269504f);
            frag[i][r] = e; sm[r] += e;
        }
    #pragma unroll
    for (int off=1; off<16; off<<=1)
        #pragma unroll
        for (int r=0;r<4;++r) sm[r] += __shfl_xor(sm[r], off);
    __syncthreads();
    if (lc == 0){ redbuf[wave][quad*4+0]=sm[0]; redbuf[wave][quad*4+1]=sm[1];
                  redbuf[wave][quad*4+2]=sm[2]; redbuf[wave][quad*4+3]=sm[3]; }
    __syncthreads();
    float inv[4];
    #pragma unroll
    for (int r=0;r<4;++r){
        int rr = quad*4+r;
        inv[r] = 1.0f / (redbuf[0][rr]+redbuf[1][rr]+redbuf[2][rr]+redbuf[3][rr]);
    }
    #pragma unroll
    for (int i=0;i<13;++i){
        int tloc = (i*4+wave)*16 + lc;
        #pragma unroll
        for (int r=0;r<4;++r){
            float p = frag[i][r] * inv[r];
            int srow = quad*4 + r;
            P_lds[srow][tloc] = f2bf(p);
            int sgr = s0 + srow;
            if (sgr < S_TOT && tloc < S_TOT)
                outP[32 + (((long)b*S_TOT + sgr)*8 + h)*S_TOT + tloc] = p;
        }
    }
    __syncthreads();
    // PV: waves (0,2) -> j 0..15, (1,3) -> j 16..31; k-chunks split even/odd
    int jt = wave & 1;
    v4f dacc = (v4f){0.f,0.f,0.f,0.f};
    #pragma unroll
    for (int i=0;i<13;++i){
        int ch = (wave>>1) + 2*i;
        v8s ap = *(const v8s*)&P_lds[lc][ch*32 + quad*8];
        v8s bv;
        #pragma unroll
        for (int j=0;j<8;++j){
            int t = ch*32 + quad*8 + j;
            float vv = (t < S_TOT) ? qkvf[((long)(b*S_TOT + t))*768 + 512 + h*32 + jt*16 + lc] : 0.f;
            bv[j] = (short)f2bf(vv);
        }
        dacc = mfma16(ap, bv, dacc);
    }
    #pragma unroll
    for (int r=0;r<4;++r) attnbuf[wave][quad*4+r][lc] = dacc[r];
    __syncthreads();
    for (int idx = tid; idx < 512; idx += 256){
        int sr = idx >> 5, j = idx & 31;
        float v = attnbuf[j>>4][sr][j&15] + attnbuf[2+(j>>4)][sr][j&15];
        v = fmaxf(v, 0.f);
        if (s0 + sr < S_TOT)
            attn_cat[((long)(b*S_TOT + s0 + sr))*256 + h*32 + j] = f2bf(v);
    }
}

// ---------------- head: partial row-sums then standardize + fc3 + softmax ----------------
__global__ void rowsum_partial(const float* __restrict__ h2, float* __restrict__ part)
{
    int b = blockIdx.x, cch = blockIdx.y, i = threadIdx.x;
    if (i >= 100) return;
    int sBeg = cch*104, sEnd = min(S_TOT, sBeg+104);
    float acc = 0.f;
    for (int s = sBeg; s < sEnd; ++s) acc += h2[((long)b*S_TOT + s)*100 + i];
    part[(b*8 + cch)*100 + i] = acc;
}

__global__ __launch_bounds__(256) void final_head(
    const float* __restrict__ part, const float* __restrict__ fc3w,
    const float* __restrict__ fc3b, float* __restrict__ outp)
{
    __shared__ float r_lds[1600];
    __shared__ float wred[2][4];
    int tid = threadIdx.x;
    float lsum = 0.f, lsq = 0.f;
    for (int idx = tid; idx < 1600; idx += 256){
        int b = idx/100, i = idx%100;
        float s = 0.f;
        for (int c=0;c<8;++c) s += part[(b*8+c)*100 + i];
        r_lds[idx] = s;
        lsum += s; lsq += s*s;
    }
    #pragma unroll
    for (int off=32; off>=1; off>>=1){
        lsum += __shfl_xor(lsum, off);
        lsq  += __shfl_xor(lsq, off);
    }
    int wave = tid >> 6;
    if ((tid & 63) == 0){ wred[0][wave] = lsum; wred[1][wave] = lsq; }
    __syncthreads();
    float S1 = wred[0][0]+wred[0][1]+wred[0][2]+wred[0][3];
    float S2 = wred[1][0]+wred[1][1]+wred[1][2]+wred[1][3];
    float mean = S1/1600.0f;
    float var = (S2 - S1*mean)/1599.0f;   // ddof=1
    float isd = rsqrtf(var);
    if (tid < 16){
        float l0 = fc3b[0], l1 = fc3b[1];
        for (int i=0;i<100;++i){
            float rn = (r_lds[tid*100+i] - mean)*isd;
            l0 += rn * fc3w[i*2+0];
            l1 += rn * fc3w[i*2+1];
        }
        float m = fmaxf(l0, l1);
        float e0 = exp2f((l0-m)*1.44269504f), e1 = exp2f((l1-m)*1.44269504f);
        float d = e0 + e1;
        outp[tid*2+0] = e0/d;
        outp[tid*2+1] = e1/d;
    }
}

extern "C" void kernel_launch(void* const* d_in, const int* in_sizes, int n_in,
                              void* d_out, int out_size, void* d_ws, size_t ws_size,
                              hipStream_t stream)
{
    const float* input_p = (const float*)d_in[0];
    const float* input_e = (const float*)d_in[1];
    const float* conv_p_w = (const float*)d_in[2];
    const float* bn_p_g = (const float*)d_in[3];
    const float* bn_p_b = (const float*)d_in[4];
    const float* bn_p_m = (const float*)d_in[5];
    const float* bn_p_v = (const float*)d_in[6];
    const float* conv_e_w = (const float*)d_in[7];
    const float* bn_e_g = (const float*)d_in[8];
    const float* bn_e_b = (const float*)d_in[9];
    const float* bn_e_m = (const float*)d_in[10];
    const float* bn_e_v = (const float*)d_in[11];
    const float* lstm_w_ih = (const float*)d_in[12];
    const float* lstm_w_hh = (const float*)d_in[13];
    const float* lstm_b_ih = (const float*)d_in[14];
    const float* lstm_b_hh = (const float*)d_in[15];
    const float* wq = (const float*)d_in[16];
    const float* bq = (const float*)d_in[17];
    const float* wk = (const float*)d_in[18];
    const float* bk = (const float*)d_in[19];
    const float* wv = (const float*)d_in[20];
    const float* bv = (const float*)d_in[21];
    const float* mh_w = (const float*)d_in[22];
    const float* mh_b = (const float*)d_in[23];
    const float* fc3_w = (const float*)d_in[24];
    const float* fc3_b = (const float*)d_in[25];
    float* out = (float*)d_out;

    char* ws = (char*)d_ws;
    size_t off = 0;
    auto alloc = [&](size_t bytes)->char*{
        char* p = ws + off; off += (bytes + 255) & ~(size_t)255; return p;
    };
    unsigned short* Xbf   = (unsigned short*)alloc((size_t)MROWS*200*2);
    float*          gatex = (float*)alloc((size_t)2*MROWS*400*4);   // reused as QKV f32
    unsigned short* H0bf  = (unsigned short*)alloc((size_t)MROWS*200*2);
    unsigned short* OUTbf = (unsigned short*)alloc((size_t)MROWS*200*2);
    unsigned short* QKVbf = (unsigned short*)alloc((size_t)MROWS*768*2);
    unsigned short* attnc = (unsigned short*)alloc((size_t)MROWS*256*2);
    float*          h2    = (float*)alloc((size_t)MROWS*100*4);
    float*          part  = (float*)alloc((size_t)16*8*100*4);
    unsigned short* WihBf = (unsigned short*)alloc(320000*2);
    float*          bias2 = (float*)alloc(3200*4);
    unsigned short* WhhBf = (unsigned short*)alloc(160000*2);
    unsigned short* wqkvT = (unsigned short*)alloc(153600*2);
    float*          qkvBias = (float*)alloc(768*4);
    unsigned short* mhwT  = (unsigned short*)alloc(25600*2);
    (void)ws_size; (void)in_sizes; (void)n_in; (void)out_size;

    prep<<<(663168+255)/256, 256, 0, stream>>>(lstm_w_ih, lstm_w_hh, lstm_b_ih, lstm_b_hh,
        wq, bq, wk, bk, wv, bv, mh_w, WihBf, bias2, WhhBf, wqkvT, qkvBias, mhwT);

    conv_pool<<<(BATCH*S_TOT*NK+255)/256, 256, 0, stream>>>(input_p, input_e,
        conv_p_w, bn_p_g, bn_p_b, bn_p_m, bn_p_v,
        conv_e_w, bn_e_g, bn_e_b, bn_e_m, bn_e_v, Xbf);

    // layer 0: gate_x GEMM (both dirs), then scan
    dim3 gGate((MROWS+63)/64, (400+63)/64, 2);
    gemm_bf16<<<gGate, 256, 0, stream>>>(Xbf, WihBf, bias2, gatex, nullptr,
        MROWS, 400, 200, (long)400*200, 400, (long)MROWS*400, 0);
    lstm_scan<<<16, 512, 0, stream>>>(gatex, WhhBf, H0bf);

    // layer 1
    gemm_bf16<<<gGate, 256, 0, stream>>>(H0bf, WihBf + 2*400*200, bias2 + 800, gatex, nullptr,
        MROWS, 400, 200, (long)400*200, 400, (long)MROWS*400, 0);
    lstm_scan<<<16, 512, 0, stream>>>(gatex, WhhBf + 2*400*100, OUTbf);

    // QKV projection (fp32 + bf16 outputs); fp32 aliases gatex (dead now)
    float* QKVf = gatex;
    dim3 gQKV((MROWS+63)/64, 768/64, 1);
    gemm_bf16<<<gQKV, 256, 0, stream>>>(OUTbf, wqkvT, qkvBias, QKVf, QKVbf,
        MROWS, 768, 200, 0, 0, 0, 0);

    // fused attention: scores -> softmax (into d_out) -> PV -> attn_cat bf16
    dim3 gAttn(52, 128);
    attn_fused<<<gAttn, 256, 0, stream>>>(QKVbf, QKVf, out, attnc);

    // mh dense + relu
    dim3 gMh((MROWS+63)/64, (100+63)/64, 1);
    gemm_bf16<<<gMh, 256, 0, stream>>>(attnc, mhwT, mh_b, h2, nullptr,
        MROWS, 100, 256, 0, 0, 0, 1);

    rowsum_partial<<<dim3(16,8), 128, 0, stream>>>(h2, part);
    final_head<<<1, 256, 0, stream>>>(part, fc3_w, fc3_b, out);
}

// Round 2
// 2418.649 us; speedup vs baseline: 2.4167x; 2.4167x over previous
//
#include <hip/hip_runtime.h>

#define S_TOT 829
#define SP 498
#define BATCH 16
#define NK 200
#define RH 100
#define DMODEL 200
#define G4 400
#define MROWS (BATCH*S_TOT)   // 13264

using v8s = __attribute__((ext_vector_type(8))) short;
using v4f = __attribute__((ext_vector_type(4))) float;

__device__ inline v4f mfma16(v8s a, v8s b, v4f c){
    return __builtin_amdgcn_mfma_f32_16x16x32_bf16(a, b, c, 0, 0, 0);
}
__device__ inline unsigned short f2bf(float f){
    unsigned int u = __float_as_uint(f);
    unsigned int r = (u + 0x7FFFu + ((u >> 16) & 1u)) >> 16;
    return (unsigned short)r;
}
__device__ inline float sigf(float x){ return 1.0f/(1.0f + exp2f(-1.44269504f*x)); }
__device__ inline float tanhfast(float x){ return 2.0f/(1.0f + exp2f(-2.88539008f*x)) - 1.0f; }

// ---------------- prep: weight conversions / transposes ----------------
__global__ void prep(const float* __restrict__ w_ih, const float* __restrict__ w_hh,
                     const float* __restrict__ b_ih, const float* __restrict__ b_hh,
                     const float* __restrict__ wq, const float* __restrict__ bq,
                     const float* __restrict__ wk, const float* __restrict__ bk,
                     const float* __restrict__ wv, const float* __restrict__ bv,
                     const float* __restrict__ mh_w,
                     unsigned short* __restrict__ WihBf, float* __restrict__ bias2,
                     unsigned short* __restrict__ WhhBf, unsigned short* __restrict__ wqkvT,
                     float* __restrict__ qkvBias, unsigned short* __restrict__ mhwT)
{
    int t = blockIdx.x*blockDim.x + threadIdx.x;
    if (t < 320000) { WihBf[t] = f2bf(w_ih[t]); }
    else if (t < 323200) { int i = t-320000; bias2[i] = b_ih[i] + b_hh[i]; }
    else if (t < 483200) { int i = t-323200; WhhBf[i] = f2bf(w_hh[i]); }
    else if (t < 636800) { int i = t-483200; int r = i/200, d = i%200;
        int which = r>>8, hh = (r>>5)&7, j = r&31;
        const float* ws = which==0?wq:(which==1?wk:wv);
        wqkvT[i] = f2bf(ws[(hh*200 + d)*32 + j]); }
    else if (t < 637568) { int r = t-636800; int which = r>>8, hh=(r>>5)&7, j=r&31;
        const float* bs = which==0?bq:(which==1?bk:bv);
        qkvBias[r] = bs[hh*32 + j]; }
    else if (t < 663168) { int i = t-637568; int n = i/256, k = i%256;
        mhwT[i] = f2bf(mh_w[k*100 + n]); }
}

// ---------------- conv + BN + ReLU + maxpool(6), writes X bf16 [B,S,200] ----------------
__global__ void conv_pool(const float* __restrict__ xp, const float* __restrict__ xe,
    const float* __restrict__ wp, const float* __restrict__ gp, const float* __restrict__ bp,
    const float* __restrict__ mp, const float* __restrict__ vp,
    const float* __restrict__ we, const float* __restrict__ ge, const float* __restrict__ be,
    const float* __restrict__ me, const float* __restrict__ ve,
    unsigned short* __restrict__ Xbf)
{
    int t = blockIdx.x*blockDim.x + threadIdx.x;
    if (t >= BATCH*S_TOT*NK) return;
    int oc = t % NK;
    int s  = (t / NK) % S_TOT;
    int b  = t / (NK*S_TOT);
    const float *x, *w, *g, *bb, *mm, *vv; int L, sl;
    if (s < SP){ x=xp; w=wp; g=gp; bb=bp; mm=mp; vv=vp; L=3000; sl=s; }
    else       { x=xe; w=we; g=ge; bb=be; mm=me; vv=ve; L=2000; sl=s-SP; }
    float inv = g[oc] * rsqrtf(vv[oc] + 1e-5f);
    float sh  = bb[oc] - mm[oc]*inv;
    int l0 = sl*6;
    const float* xb = x + (long)b*4*L;
    const float* wo = w + oc*52;
    float best = -1e30f;
    for (int u=0; u<6; ++u){
        float a = 0.f;
        #pragma unroll
        for (int ic=0; ic<4; ++ic){
            const float* xr = xb + ic*L + l0 + u;
            const float* wr = wo + ic*13;
            #pragma unroll
            for (int k=0; k<13; ++k) a += xr[k]*wr[k];
        }
        best = fmaxf(best, a*inv + sh);
    }
    Xbf[t] = f2bf(fmaxf(best, 0.f));
}

// ---------------- generic bf16 MFMA GEMM: C[z] = A @ B[z]^T (+bias, relu) ----------------
__global__ __launch_bounds__(256) void gemm_bf16(
    const unsigned short* __restrict__ A, const unsigned short* __restrict__ B,
    const float* __restrict__ bias, float* __restrict__ C, unsigned short* __restrict__ Cbf,
    int M, int N, int K, long strideB, long strideBias, long strideC, int relu)
{
    __shared__ unsigned short As[64][40];
    __shared__ unsigned short Bs[64][40];
    int tid = threadIdx.x;
    int m0 = blockIdx.x*64, n0 = blockIdx.y*64, z = blockIdx.z;
    const unsigned short* Bz = B + z*strideB;
    const float* biasz = bias + z*strideBias;
    float* Cz = C + z*strideC;
    unsigned short* Cbz = Cbf ? Cbf + z*strideC : nullptr;

    int lane = tid & 63, wave = tid >> 6;
    int wm = wave >> 1, wn = wave & 1;
    int quad = lane >> 4, lc = lane & 15;
    int row = tid >> 2, seg = tid & 3;

    v4f acc[2][2];
    #pragma unroll
    for (int i=0;i<2;++i)
      #pragma unroll
      for (int j=0;j<2;++j) acc[i][j] = (v4f){0.f,0.f,0.f,0.f};

    int KC = (K + 31) >> 5;
    for (int kc = 0; kc < KC; ++kc){
        int k0 = kc << 5;
        __syncthreads();
        {
            int gm = m0 + row, gn = n0 + row, ks = k0 + seg*8;
            if (gm < M && ks + 8 <= K)
                *(v8s*)&As[row][seg*8] = *(const v8s*)(A + (long)gm*K + ks);
            else
                for (int j=0;j<8;++j) As[row][seg*8+j] = (gm<M && ks+j<K) ? A[(long)gm*K+ks+j] : 0;
            if (gn < N && ks + 8 <= K)
                *(v8s*)&Bs[row][seg*8] = *(const v8s*)(Bz + (long)gn*K + ks);
            else
                for (int j=0;j<8;++j) Bs[row][seg*8+j] = (gn<N && ks+j<K) ? Bz[(long)gn*K+ks+j] : 0;
        }
        __syncthreads();
        v8s a0 = *(const v8s*)&As[wm*32 + lc][quad*8];
        v8s a1 = *(const v8s*)&As[wm*32 + 16 + lc][quad*8];
        v8s b0 = *(const v8s*)&Bs[wn*32 + lc][quad*8];
        v8s b1 = *(const v8s*)&Bs[wn*32 + 16 + lc][quad*8];
        acc[0][0] = mfma16(a0, b0, acc[0][0]);
        acc[0][1] = mfma16(a0, b1, acc[0][1]);
        acc[1][0] = mfma16(a1, b0, acc[1][0]);
        acc[1][1] = mfma16(a1, b1, acc[1][1]);
    }
    #pragma unroll
    for (int i=0;i<2;++i)
      #pragma unroll
      for (int j=0;j<2;++j){
        int nc = n0 + wn*32 + j*16 + lc;
        #pragma unroll
        for (int r=0;r<4;++r){
            int mr = m0 + wm*32 + i*16 + quad*4 + r;
            if (mr < M && nc < N){
                float v = acc[i][j][r] + biasz[nc];
                if (relu) v = fmaxf(v, 0.f);
                Cz[(long)mr*N + nc] = v;
                if (Cbz) Cbz[(long)mr*N + nc] = f2bf(v);
            }
        }
      }
}

// ---------------- persistent LSTM scan: 1 block per (dir, 2-batch group) ----------------
// Known-good structure (gates-LDS roundtrip, 200 act threads, coalesced access)
// + ONLY change: gx register-prefetched 2 steps ahead, and barriers are raw
// s_barrier with lgkmcnt-only drain so the prefetch loads stay in flight
// across barriers (a __syncthreads would drain vmcnt(0) and kill the prefetch).
__global__ __launch_bounds__(512) void lstm_scan(
    const float* __restrict__ gx, const unsigned short* __restrict__ whh,
    unsigned short* __restrict__ Hout)
{
    __shared__ unsigned short h_bf[16][136];  // bf16 h, k-padded to 128 (+8 stride pad)
    __shared__ float gates[2][408];
    int tid = threadIdx.x;
    int dir = blockIdx.x >> 3, bg = blockIdx.x & 7;
    int b0 = bg*2;
    int lane = tid & 63, wave = tid >> 6;
    int quad = lane >> 4, lc = lane & 15;

    for (int idx = tid; idx < 16*136; idx += 512) ((unsigned short*)h_bf)[idx] = 0;

    // register-resident W_hh B-fragments: wave w owns n-tiles {w, w+8, w+16, w+24} (<25)
    const unsigned short* W = whh + dir*G4*RH;
    v8s bfr[4][4];
    #pragma unroll
    for (int i=0;i<4;++i){
        int nt = wave + 8*i;
        #pragma unroll
        for (int kc=0;kc<4;++kc){
            v8s v;
            #pragma unroll
            for (int j=0;j<8;++j){
                int n = nt*16 + lc, k = kc*32 + quad*8 + j;
                v[j] = (nt<25 && k<RH) ? (short)W[n*RH + k] : (short)0;
            }
            bfr[i][kc] = v;
        }
    }
    bool act = tid < 200;
    int b_l = tid/100, nn = tid%100;
    long gbase = (((long)dir*BATCH + (b0+b_l))*S_TOT)*(long)G4 + nn;
    float creg = 0.f;

    // 2-step-ahead register prefetch buffers (even steps -> gA, odd -> gB)
    float gA[4], gB[4];
    auto loadg = [&](float (&g)[4], int t){
        if (act && t < S_TOT){
            int s = dir ? (S_TOT-1-t) : t;
            const float* gp = gx + gbase + (long)s*G4;
            g[0] = gp[0]; g[1] = gp[100]; g[2] = gp[200]; g[3] = gp[300];
        }
    };
    loadg(gA, 0);
    loadg(gB, 1);
    __syncthreads();   // once, before the scan loop

    auto bar = [&](){
        asm volatile("s_waitcnt lgkmcnt(0)" ::: "memory");
        __builtin_amdgcn_s_barrier();
    };

    auto step = [&](int t, float (&g)[4]){
        int s = dir ? (S_TOT-1-t) : t;
        v8s afr[4];
        #pragma unroll
        for (int kc=0;kc<4;++kc)
            afr[kc] = *(const v8s*)&h_bf[lc][kc*32 + quad*8];
        #pragma unroll
        for (int i=0;i<4;++i){
            int nt = wave + 8*i;
            if (nt < 25){
                v4f d0 = (v4f){0.f,0.f,0.f,0.f}, d1 = (v4f){0.f,0.f,0.f,0.f};
                d0 = mfma16(afr[0], bfr[i][0], d0);
                d1 = mfma16(afr[1], bfr[i][1], d1);
                d0 = mfma16(afr[2], bfr[i][2], d0);
                d1 = mfma16(afr[3], bfr[i][3], d1);
                if (lane < 16){           // D rows 0,1 live in quad 0, regs 0,1
                    gates[0][nt*16+lc] = d0[0] + d1[0];
                    gates[1][nt*16+lc] = d0[1] + d1[1];
                }
            }
        }
        bar();                             // gates visible to act threads
        if (act){
            float gi = gates[b_l][nn]     + g[0];
            float gf = gates[b_l][100+nn] + g[1];
            float gg = gates[b_l][200+nn] + g[2];
            float go = gates[b_l][300+nn] + g[3];
            creg = sigf(gf)*creg + sigf(gi)*tanhfast(gg);
            float h = sigf(go) * tanhfast(creg);
            unsigned short hb = f2bf(h);
            h_bf[b_l][nn] = hb;
            Hout[((long)(b0+b_l)*S_TOT + s)*DMODEL + dir*RH + nn] = hb;
        }
        loadg(g, t+2);                     // refill buffer just consumed
        bar();                             // h_bf visible to all waves
    };

    for (int t=0; t+1 < S_TOT; t += 2){
        step(t,   gA);
        step(t+1, gB);
    }
    step(S_TOT-1, gA);   // S_TOT odd: final even step consumes gA
}

// ---------------- fused scores + softmax + PV, per (b,h,s-tile of 16) ----------------
__global__ __launch_bounds__(256) void attn_fused(
    const unsigned short* __restrict__ qkvbf, const float* __restrict__ qkvf,
    float* __restrict__ outP, unsigned short* __restrict__ attn_cat)
{
    __shared__ unsigned short P_lds[16][840];
    __shared__ float redbuf[4][16];
    __shared__ float attnbuf[4][16][17];
    int tid = threadIdx.x;
    int lane = tid & 63, wave = tid >> 6;
    int quad = lane >> 4, lc = lane & 15;
    int b = blockIdx.y >> 3, h = blockIdx.y & 7;
    int s0 = blockIdx.x*16;
    const float scale = 0.17677669529663687f;

    v8s aq = (v8s){0,0,0,0,0,0,0,0};
    int sg = s0 + lc;
    if (sg < S_TOT) aq = *(const v8s*)(qkvbf + ((long)(b*S_TOT + sg))*768 + h*32 + quad*8);

    v4f frag[13];
    #pragma unroll
    for (int i=0;i<13;++i){
        int tg = (i*4 + wave)*16 + lc;
        v8s bk = (v8s){0,0,0,0,0,0,0,0};
        if (tg < S_TOT) bk = *(const v8s*)(qkvbf + ((long)(b*S_TOT + tg))*768 + 256 + h*32 + quad*8);
        v4f z = (v4f){0.f,0.f,0.f,0.f};
        frag[i] = mfma16(aq, bk, z);
    }
    float mx[4] = {-1e30f,-1e30f,-1e30f,-1e30f};
    #pragma unroll
    for (int i=0;i<13;++i){
        int tcol = (i*4+wave)*16 + lc;
        bool tv = tcol < S_TOT;
        #pragma unroll
        for (int r=0;r<4;++r){
            float x = tv ? frag[i][r]*scale : -1e30f;
            frag[i][r] = x;
            mx[r] = fmaxf(mx[r], x);
        }
    }
    #pragma unroll
    for (int off=1; off<16; off<<=1)
        #pragma unroll
        for (int r=0;r<4;++r) mx[r] = fmaxf(mx[r], __shfl_xor(mx[r], off));
    if (lc == 0){ redbuf[wave][quad*4+0]=mx[0]; redbuf[wave][quad*4+1]=mx[1];
                  redbuf[wave][quad*4+2]=mx[2]; redbuf[wave][quad*4+3]=mx[3]; }
    __syncthreads();
    float M4[4], sm[4] = {0.f,0.f,0.f,0.f};
    #pragma unroll
    for (int r=0;r<4;++r){
        int rr = quad*4+r;
        M4[r] = fmaxf(fmaxf(redbuf[0][rr], redbuf[1][rr]), fmaxf(redbuf[2][rr], redbuf[3][rr]));
    }
    #pragma unroll
    for (int i=0;i<13;++i)
        #pragma unroll
        for (int r=0;r<4;++r){
            float e = exp2f((frag[i][r] - M4[r]) * 1.44269504f);
            frag[i][r] = e; sm[r] += e;
        }
    #pragma unroll
    for (int off=1; off<16; off<<=1)
        #pragma unroll
        for (int r=0;r<4;++r) sm[r] += __shfl_xor(sm[r], off);
    __syncthreads();
    if (lc == 0){ redbuf[wave][quad*4+0]=sm[0]; redbuf[wave][quad*4+1]=sm[1];
                  redbuf[wave][quad*4+2]=sm[2]; redbuf[wave][quad*4+3]=sm[3]; }
    __syncthreads();
    float inv[4];
    #pragma unroll
    for (int r=0;r<4;++r){
        int rr = quad*4+r;
        inv[r] = 1.0f / (redbuf[0][rr]+redbuf[1][rr]+redbuf[2][rr]+redbuf[3][rr]);
    }
    #pragma unroll
    for (int i=0;i<13;++i){
        int tloc = (i*4+wave)*16 + lc;
        #pragma unroll
        for (int r=0;r<4;++r){
            float p = frag[i][r] * inv[r];
            int srow = quad*4 + r;
            P_lds[srow][tloc] = f2bf(p);
            int sgr = s0 + srow;
            if (sgr < S_TOT && tloc < S_TOT)
                outP[32 + (((long)b*S_TOT + sgr)*8 + h)*S_TOT + tloc] = p;
        }
    }
    __syncthreads();
    // PV: waves (0,2) -> j 0..15, (1,3) -> j 16..31; k-chunks split even/odd
    int jt = wave & 1;
    v4f dacc = (v4f){0.f,0.f,0.f,0.f};
    #pragma unroll
    for (int i=0;i<13;++i){
        int ch = (wave>>1) + 2*i;
        v8s ap = *(const v8s*)&P_lds[lc][ch*32 + quad*8];
        v8s bv;
        #pragma unroll
        for (int j=0;j<8;++j){
            int t = ch*32 + quad*8 + j;
            float vv = (t < S_TOT) ? qkvf[((long)(b*S_TOT + t))*768 + 512 + h*32 + jt*16 + lc] : 0.f;
            bv[j] = (short)f2bf(vv);
        }
        dacc = mfma16(ap, bv, dacc);
    }
    #pragma unroll
    for (int r=0;r<4;++r) attnbuf[wave][quad*4+r][lc] = dacc[r];
    __syncthreads();
    for (int idx = tid; idx < 512; idx += 256){
        int sr = idx >> 5, j = idx & 31;
        float v = attnbuf[j>>4][sr][j&15] + attnbuf[2+(j>>4)][sr][j&15];
        v = fmaxf(v, 0.f);
        if (s0 + sr < S_TOT)
            attn_cat[((long)(b*S_TOT + s0 + sr))*256 + h*32 + j] = f2bf(v);
    }
}

// ---------------- head: partial row-sums then standardize + fc3 + softmax ----------------
__global__ void rowsum_partial(const float* __restrict__ h2, float* __restrict__ part)
{
    int b = blockIdx.x, cch = blockIdx.y, i = threadIdx.x;
    if (i >= 100) return;
    int sBeg = cch*104, sEnd = min(S_TOT, sBeg+104);
    float acc = 0.f;
    for (int s = sBeg; s < sEnd; ++s) acc += h2[((long)b*S_TOT + s)*100 + i];
    part[(b*8 + cch)*100 + i] = acc;
}

__global__ __launch_bounds__(256) void final_head(
    const float* __restrict__ part, const float* __restrict__ fc3w,
    const float* __restrict__ fc3b, float* __restrict__ outp)
{
    __shared__ float r_lds[1600];
    __shared__ float wred[2][4];
    int tid = threadIdx.x;
    float lsum = 0.f, lsq = 0.f;
    for (int idx = tid; idx < 1600; idx += 256){
        int b = idx/100, i = idx%100;
        float s = 0.f;
        for (int c=0;c<8;++c) s += part[(b*8+c)*100 + i];
        r_lds[idx] = s;
        lsum += s; lsq += s*s;
    }
    #pragma unroll
    for (int off=32; off>=1; off>>=1){
        lsum += __shfl_xor(lsum, off);
        lsq  += __shfl_xor(lsq, off);
    }
    int wave = tid >> 6;
    if ((tid & 63) == 0){ wred[0][wave] = lsum; wred[1][wave] = lsq; }
    __syncthreads();
    float S1 = wred[0][0]+wred[0][1]+wred[0][2]+wred[0][3];
    float S2 = wred[1][0]+wred[1][1]+wred[1][2]+wred[1][3];
    float mean = S1/1600.0f;
    float var = (S2 - S1*mean)/1599.0f;   // ddof=1
    float isd = rsqrtf(var);
    if (tid < 16){
        float l0 = fc3b[0], l1 = fc3b[1];
        for (int i=0;i<100;++i){
            float rn = (r_lds[tid*100+i] - mean)*isd;
            l0 += rn * fc3w[i*2+0];
            l1 += rn * fc3w[i*2+1];
        }
        float m = fmaxf(l0, l1);
        float e0 = exp2f((l0-m)*1.44269504f), e1 = exp2f((l1-m)*1.44269504f);
        float d = e0 + e1;
        outp[tid*2+0] = e0/d;
        outp[tid*2+1] = e1/d;
    }
}

extern "C" void kernel_launch(void* const* d_in, const int* in_sizes, int n_in,
                              void* d_out, int out_size, void* d_ws, size_t ws_size,
                              hipStream_t stream)
{
    const float* input_p = (const float*)d_in[0];
    const float* input_e = (const float*)d_in[1];
    const float* conv_p_w = (const float*)d_in[2];
    const float* bn_p_g = (const float*)d_in[3];
    const float* bn_p_b = (const float*)d_in[4];
    const float* bn_p_m = (const float*)d_in[5];
    const float* bn_p_v = (const float*)d_in[6];
    const float* conv_e_w = (const float*)d_in[7];
    const float* bn_e_g = (const float*)d_in[8];
    const float* bn_e_b = (const float*)d_in[9];
    const float* bn_e_m = (const float*)d_in[10];
    const float* bn_e_v = (const float*)d_in[11];
    const float* lstm_w_ih = (const float*)d_in[12];
    const float* lstm_w_hh = (const float*)d_in[13];
    const float* lstm_b_ih = (const float*)d_in[14];
    const float* lstm_b_hh = (const float*)d_in[15];
    const float* wq = (const float*)d_in[16];
    const float* bq = (const float*)d_in[17];
    const float* wk = (const float*)d_in[18];
    const float* bk = (const float*)d_in[19];
    const float* wv = (const float*)d_in[20];
    const float* bv = (const float*)d_in[21];
    const float* mh_w = (const float*)d_in[22];
    const float* mh_b = (const float*)d_in[23];
    const float* fc3_w = (const float*)d_in[24];
    const float* fc3_b = (const float*)d_in[25];
    float* out = (float*)d_out;

    char* ws = (char*)d_ws;
    size_t off = 0;
    auto alloc = [&](size_t bytes)->char*{
        char* p = ws + off; off += (bytes + 255) & ~(size_t)255; return p;
    };
    unsigned short* Xbf   = (unsigned short*)alloc((size_t)MROWS*200*2);
    float*          gatex = (float*)alloc((size_t)2*MROWS*400*4);   // reused as QKV f32
    unsigned short* H0bf  = (unsigned short*)alloc((size_t)MROWS*200*2);
    unsigned short* OUTbf = (unsigned short*)alloc((size_t)MROWS*200*2);
    unsigned short* QKVbf = (unsigned short*)alloc((size_t)MROWS*768*2);
    unsigned short* attnc = (unsigned short*)alloc((size_t)MROWS*256*2);
    float*          h2    = (float*)alloc((size_t)MROWS*100*4);
    float*          part  = (float*)alloc((size_t)16*8*100*4);
    unsigned short* WihBf = (unsigned short*)alloc(320000*2);
    float*          bias2 = (float*)alloc(3200*4);
    unsigned short* WhhBf = (unsigned short*)alloc(160000*2);
    unsigned short* wqkvT = (unsigned short*)alloc(153600*2);
    float*          qkvBias = (float*)alloc(768*4);
    unsigned short* mhwT  = (unsigned short*)alloc(25600*2);
    (void)ws_size; (void)in_sizes; (void)n_in; (void)out_size;

    prep<<<(663168+255)/256, 256, 0, stream>>>(lstm_w_ih, lstm_w_hh, lstm_b_ih, lstm_b_hh,
        wq, bq, wk, bk, wv, bv, mh_w, WihBf, bias2, WhhBf, wqkvT, qkvBias, mhwT);

    conv_pool<<<(BATCH*S_TOT*NK+255)/256, 256, 0, stream>>>(input_p, input_e,
        conv_p_w, bn_p_g, bn_p_b, bn_p_m, bn_p_v,
        conv_e_w, bn_e_g, bn_e_b, bn_e_m, bn_e_v, Xbf);

    // layer 0: gate_x GEMM (both dirs), then scan
    dim3 gGate((MROWS+63)/64, (400+63)/64, 2);
    gemm_bf16<<<gGate, 256, 0, stream>>>(Xbf, WihBf, bias2, gatex, nullptr,
        MROWS, 400, 200, (long)400*200, 400, (long)MROWS*400, 0);
    lstm_scan<<<16, 512, 0, stream>>>(gatex, WhhBf, H0bf);

    // layer 1
    gemm_bf16<<<gGate, 256, 0, stream>>>(H0bf, WihBf + 2*400*200, bias2 + 800, gatex, nullptr,
        MROWS, 400, 200, (long)400*200, 400, (long)MROWS*400, 0);
    lstm_scan<<<16, 512, 0, stream>>>(gatex, WhhBf + 2*400*100, OUTbf);

    // QKV projection (fp32 + bf16 outputs); fp32 aliases gatex (dead now)
    float* QKVf = gatex;
    dim3 gQKV((MROWS+63)/64, 768/64, 1);
    gemm_bf16<<<gQKV, 256, 0, stream>>>(OUTbf, wqkvT, qkvBias, QKVf, QKVbf,
        MROWS, 768, 200, 0, 0, 0, 0);

    // fused attention: scores -> softmax (into d_out) -> PV -> attn_cat bf16
    dim3 gAttn(52, 128);
    attn_fused<<<gAttn, 256, 0, stream>>>(QKVbf, QKVf, out, attnc);

    // mh dense + relu
    dim3 gMh((MROWS+63)/64, (100+63)/64, 1);
    gemm_bf16<<<gMh, 256, 0, stream>>>(attnc, mhwT, mh_b, h2, nullptr,
        MROWS, 100, 256, 0, 0, 0, 1);

    rowsum_partial<<<dim3(16,8), 128, 0, stream>>>(h2, part);
    final_head<<<1, 256, 0, stream>>>(part, fc3_w, fc3_b, out);
}

// Round 3
// 1873.792 us; speedup vs baseline: 3.1195x; 1.2908x over previous
//
#include <hip/hip_runtime.h>

#define S_TOT 829
#define SP 498
#define BATCH 16
#define NK 200
#define RH 100
#define DMODEL 200
#define G4 400
#define MROWS (BATCH*S_TOT)   // 13264
#define CTS 32                // pooled positions per conv tile
#define PTILES 16             // ceil(498/32)
#define ETILES 11             // ceil(331/32)

using v8s = __attribute__((ext_vector_type(8))) short;
using v4f = __attribute__((ext_vector_type(4))) float;

__device__ inline v4f mfma16(v8s a, v8s b, v4f c){
    return __builtin_amdgcn_mfma_f32_16x16x32_bf16(a, b, c, 0, 0, 0);
}
__device__ inline unsigned short f2bf(float f){
    unsigned int u = __float_as_uint(f);
    unsigned int r = (u + 0x7FFFu + ((u >> 16) & 1u)) >> 16;
    return (unsigned short)r;
}
__device__ inline float sigf(float x){ return 1.0f/(1.0f + exp2f(-1.44269504f*x)); }
__device__ inline float tanhfast(float x){ return 2.0f/(1.0f + exp2f(-2.88539008f*x)) - 1.0f; }

// ---------------- prep: weight conversions / transposes ----------------
__global__ void prep(const float* __restrict__ w_ih, const float* __restrict__ w_hh,
                     const float* __restrict__ b_ih, const float* __restrict__ b_hh,
                     const float* __restrict__ wq, const float* __restrict__ bq,
                     const float* __restrict__ wk, const float* __restrict__ bk,
                     const float* __restrict__ wv, const float* __restrict__ bv,
                     const float* __restrict__ mh_w,
                     unsigned short* __restrict__ WihBf, float* __restrict__ bias2,
                     unsigned short* __restrict__ WhhBf, unsigned short* __restrict__ wqkvT,
                     float* __restrict__ qkvBias, unsigned short* __restrict__ mhwT)
{
    int t = blockIdx.x*blockDim.x + threadIdx.x;
    if (t < 320000) { WihBf[t] = f2bf(w_ih[t]); }
    else if (t < 323200) { int i = t-320000; bias2[i] = b_ih[i] + b_hh[i]; }
    else if (t < 483200) { int i = t-323200; WhhBf[i] = f2bf(w_hh[i]); }
    else if (t < 636800) { int i = t-483200; int r = i/200, d = i%200;
        int which = r>>8, hh = (r>>5)&7, j = r&31;
        const float* ws = which==0?wq:(which==1?wk:wv);
        wqkvT[i] = f2bf(ws[(hh*200 + d)*32 + j]); }
    else if (t < 637568) { int r = t-636800; int which = r>>8, hh=(r>>5)&7, j=r&31;
        const float* bs = which==0?bq:(which==1?bk:bv);
        qkvBias[r] = bs[hh*32 + j]; }
    else if (t < 663168) { int i = t-637568; int n = i/256, k = i%256;
        mhwT[i] = f2bf(mh_w[k*100 + n]); }
}

// ---------------- conv + BN + ReLU + maxpool(6), LDS-tiled ----------------
// One block per (tile, batch). Weights (41.6 KB) + x window (<=3.3 KB) staged
// in LDS with coalesced loads; thread oc keeps its 52 weights in registers and
// computes CTS pooled outputs. Same fp32 accumulation order as before.
__global__ __launch_bounds__(256) void conv_pool(
    const float* __restrict__ xp, const float* __restrict__ xe,
    const float* __restrict__ wp, const float* __restrict__ gp, const float* __restrict__ bp,
    const float* __restrict__ mp, const float* __restrict__ vp,
    const float* __restrict__ we, const float* __restrict__ ge, const float* __restrict__ be,
    const float* __restrict__ me, const float* __restrict__ ve,
    unsigned short* __restrict__ Xbf)
{
    __shared__ float wlds[NK*52];
    __shared__ float xlds[4][CTS*6 + 12];
    int tile = blockIdx.x, b = blockIdx.y;
    const float *x, *w, *g, *bb, *mm, *vv; int L, S, st, sbase;
    if (tile < PTILES){ x=xp; w=wp; g=gp; bb=bp; mm=mp; vv=vp; L=3000; S=SP;      st=tile*CTS;          sbase=0;  }
    else              { x=xe; w=we; g=ge; bb=be; mm=me; vv=ve; L=2000; S=S_TOT-SP; st=(tile-PTILES)*CTS; sbase=SP; }
    int tid = threadIdx.x;
    int scount = min(CTS, S - st);
    int r0 = st*6;
    int ext = scount*6 + 12;

    for (int i = tid; i < NK*52; i += 256) wlds[i] = w[i];
    for (int i = tid; i < 4*ext; i += 256){
        int ic = i/ext, j = i%ext;
        xlds[ic][j] = x[(long)b*4*L + ic*L + r0 + j];
    }
    __syncthreads();

    int oc = tid;
    if (oc < NK){
        float wreg[52];
        #pragma unroll
        for (int j=0;j<52;++j) wreg[j] = wlds[oc*52 + j];
        float inv = g[oc] * rsqrtf(vv[oc] + 1e-5f);
        float sh  = bb[oc] - mm[oc]*inv;
        for (int sl = 0; sl < scount; ++sl){
            float xw[4][18];
            #pragma unroll
            for (int ic=0;ic<4;++ic)
                #pragma unroll
                for (int j=0;j<18;++j) xw[ic][j] = xlds[ic][sl*6 + j];
            float best = -1e30f;
            #pragma unroll
            for (int u=0; u<6; ++u){
                float a = 0.f;
                #pragma unroll
                for (int ic=0; ic<4; ++ic)
                    #pragma unroll
                    for (int k=0; k<13; ++k) a += xw[ic][u+k] * wreg[ic*13+k];
                best = fmaxf(best, a*inv + sh);
            }
            Xbf[((long)b*S_TOT + sbase + st + sl)*NK + oc] = f2bf(fmaxf(best, 0.f));
        }
    }
}

// ---------------- generic bf16 MFMA GEMM: C[z] = A @ B[z]^T (+bias, relu) ----------------
__global__ __launch_bounds__(256) void gemm_bf16(
    const unsigned short* __restrict__ A, const unsigned short* __restrict__ B,
    const float* __restrict__ bias, float* __restrict__ C, unsigned short* __restrict__ Cbf,
    int M, int N, int K, long strideB, long strideBias, long strideC, int relu)
{
    __shared__ unsigned short As[64][40];
    __shared__ unsigned short Bs[64][40];
    int tid = threadIdx.x;
    int m0 = blockIdx.x*64, n0 = blockIdx.y*64, z = blockIdx.z;
    const unsigned short* Bz = B + z*strideB;
    const float* biasz = bias + z*strideBias;
    float* Cz = C + z*strideC;
    unsigned short* Cbz = Cbf ? Cbf + z*strideC : nullptr;

    int lane = tid & 63, wave = tid >> 6;
    int wm = wave >> 1, wn = wave & 1;
    int quad = lane >> 4, lc = lane & 15;
    int row = tid >> 2, seg = tid & 3;

    v4f acc[2][2];
    #pragma unroll
    for (int i=0;i<2;++i)
      #pragma unroll
      for (int j=0;j<2;++j) acc[i][j] = (v4f){0.f,0.f,0.f,0.f};

    int KC = (K + 31) >> 5;
    for (int kc = 0; kc < KC; ++kc){
        int k0 = kc << 5;
        __syncthreads();
        {
            int gm = m0 + row, gn = n0 + row, ks = k0 + seg*8;
            if (gm < M && ks + 8 <= K)
                *(v8s*)&As[row][seg*8] = *(const v8s*)(A + (long)gm*K + ks);
            else
                for (int j=0;j<8;++j) As[row][seg*8+j] = (gm<M && ks+j<K) ? A[(long)gm*K+ks+j] : 0;
            if (gn < N && ks + 8 <= K)
                *(v8s*)&Bs[row][seg*8] = *(const v8s*)(Bz + (long)gn*K + ks);
            else
                for (int j=0;j<8;++j) Bs[row][seg*8+j] = (gn<N && ks+j<K) ? Bz[(long)gn*K+ks+j] : 0;
        }
        __syncthreads();
        v8s a0 = *(const v8s*)&As[wm*32 + lc][quad*8];
        v8s a1 = *(const v8s*)&As[wm*32 + 16 + lc][quad*8];
        v8s b0 = *(const v8s*)&Bs[wn*32 + lc][quad*8];
        v8s b1 = *(const v8s*)&Bs[wn*32 + 16 + lc][quad*8];
        acc[0][0] = mfma16(a0, b0, acc[0][0]);
        acc[0][1] = mfma16(a0, b1, acc[0][1]);
        acc[1][0] = mfma16(a1, b0, acc[1][0]);
        acc[1][1] = mfma16(a1, b1, acc[1][1]);
    }
    #pragma unroll
    for (int i=0;i<2;++i)
      #pragma unroll
      for (int j=0;j<2;++j){
        int nc = n0 + wn*32 + j*16 + lc;
        #pragma unroll
        for (int r=0;r<4;++r){
            int mr = m0 + wm*32 + i*16 + quad*4 + r;
            if (mr < M && nc < N){
                float v = acc[i][j][r] + biasz[nc];
                if (relu) v = fmaxf(v, 0.f);
                Cz[(long)mr*N + nc] = v;
                if (Cbz) Cbz[(long)mr*N + nc] = f2bf(v);
            }
        }
      }
}

// ---------------- persistent LSTM scan: 1 block per (dir, 2-batch group) ----------------
// Known-good structure + gx register-prefetch 2 steps ahead; raw s_barrier with
// lgkmcnt-only drain so prefetch loads stay in flight across barriers.
__global__ __launch_bounds__(512) void lstm_scan(
    const float* __restrict__ gx, const unsigned short* __restrict__ whh,
    unsigned short* __restrict__ Hout)
{
    __shared__ unsigned short h_bf[16][136];  // bf16 h, k-padded to 128 (+8 stride pad)
    __shared__ float gates[2][408];
    int tid = threadIdx.x;
    int dir = blockIdx.x >> 3, bg = blockIdx.x & 7;
    int b0 = bg*2;
    int lane = tid & 63, wave = tid >> 6;
    int quad = lane >> 4, lc = lane & 15;

    for (int idx = tid; idx < 16*136; idx += 512) ((unsigned short*)h_bf)[idx] = 0;

    // register-resident W_hh B-fragments: wave w owns n-tiles {w, w+8, w+16, w+24} (<25)
    const unsigned short* W = whh + dir*G4*RH;
    v8s bfr[4][4];
    #pragma unroll
    for (int i=0;i<4;++i){
        int nt = wave + 8*i;
        #pragma unroll
        for (int kc=0;kc<4;++kc){
            v8s v;
            #pragma unroll
            for (int j=0;j<8;++j){
                int n = nt*16 + lc, k = kc*32 + quad*8 + j;
                v[j] = (nt<25 && k<RH) ? (short)W[n*RH + k] : (short)0;
            }
            bfr[i][kc] = v;
        }
    }
    bool act = tid < 200;
    int b_l = tid/100, nn = tid%100;
    long gbase = (((long)dir*BATCH + (b0+b_l))*S_TOT)*(long)G4 + nn;
    float creg = 0.f;

    // 2-step-ahead register prefetch buffers (even steps -> gA, odd -> gB)
    float gA[4], gB[4];
    auto loadg = [&](float (&g)[4], int t){
        if (act && t < S_TOT){
            int s = dir ? (S_TOT-1-t) : t;
            const float* gp = gx + gbase + (long)s*G4;
            g[0] = gp[0]; g[1] = gp[100]; g[2] = gp[200]; g[3] = gp[300];
        }
    };
    loadg(gA, 0);
    loadg(gB, 1);
    __syncthreads();   // once, before the scan loop

    auto bar = [&](){
        asm volatile("s_waitcnt lgkmcnt(0)" ::: "memory");
        __builtin_amdgcn_s_barrier();
    };

    auto step = [&](int t, float (&g)[4]){
        int s = dir ? (S_TOT-1-t) : t;
        v8s afr[4];
        #pragma unroll
        for (int kc=0;kc<4;++kc)
            afr[kc] = *(const v8s*)&h_bf[lc][kc*32 + quad*8];
        #pragma unroll
        for (int i=0;i<4;++i){
            int nt = wave + 8*i;
            if (nt < 25){
                v4f d0 = (v4f){0.f,0.f,0.f,0.f}, d1 = (v4f){0.f,0.f,0.f,0.f};
                d0 = mfma16(afr[0], bfr[i][0], d0);
                d1 = mfma16(afr[1], bfr[i][1], d1);
                d0 = mfma16(afr[2], bfr[i][2], d0);
                d1 = mfma16(afr[3], bfr[i][3], d1);
                if (lane < 16){           // D rows 0,1 live in quad 0, regs 0,1
                    gates[0][nt*16+lc] = d0[0] + d1[0];
                    gates[1][nt*16+lc] = d0[1] + d1[1];
                }
            }
        }
        bar();                             // gates visible to act threads
        if (act){
            float gi = gates[b_l][nn]     + g[0];
            float gf = gates[b_l][100+nn] + g[1];
            float gg = gates[b_l][200+nn] + g[2];
            float go = gates[b_l][300+nn] + g[3];
            creg = sigf(gf)*creg + sigf(gi)*tanhfast(gg);
            float h = sigf(go) * tanhfast(creg);
            unsigned short hb = f2bf(h);
            h_bf[b_l][nn] = hb;
            Hout[((long)(b0+b_l)*S_TOT + s)*DMODEL + dir*RH + nn] = hb;
        }
        loadg(g, t+2);                     // refill buffer just consumed
        bar();                             // h_bf visible to all waves
    };

    for (int t=0; t+1 < S_TOT; t += 2){
        step(t,   gA);
        step(t+1, gB);
    }
    step(S_TOT-1, gA);   // S_TOT odd: final even step consumes gA
}

// ---------------- fused scores + softmax + PV, per (b,h,s-tile of 16) ----------------
__global__ __launch_bounds__(256) void attn_fused(
    const unsigned short* __restrict__ qkvbf, const float* __restrict__ qkvf,
    float* __restrict__ outP, unsigned short* __restrict__ attn_cat)
{
    __shared__ unsigned short P_lds[16][840];
    __shared__ float redbuf[4][16];
    __shared__ float attnbuf[4][16][17];
    int tid = threadIdx.x;
    int lane = tid & 63, wave = tid >> 6;
    int quad = lane >> 4, lc = lane & 15;
    int b = blockIdx.y >> 3, h = blockIdx.y & 7;
    int s0 = blockIdx.x*16;
    const float scale = 0.17677669529663687f;

    v8s aq = (v8s){0,0,0,0,0,0,0,0};
    int sg = s0 + lc;
    if (sg < S_TOT) aq = *(const v8s*)(qkvbf + ((long)(b*S_TOT + sg))*768 + h*32 + quad*8);

    v4f frag[13];
    #pragma unroll
    for (int i=0;i<13;++i){
        int tg = (i*4 + wave)*16 + lc;
        v8s bk = (v8s){0,0,0,0,0,0,0,0};
        if (tg < S_TOT) bk = *(const v8s*)(qkvbf + ((long)(b*S_TOT + tg))*768 + 256 + h*32 + quad*8);
        v4f z = (v4f){0.f,0.f,0.f,0.f};
        frag[i] = mfma16(aq, bk, z);
    }
    float mx[4] = {-1e30f,-1e30f,-1e30f,-1e30f};
    #pragma unroll
    for (int i=0;i<13;++i){
        int tcol = (i*4+wave)*16 + lc;
        bool tv = tcol < S_TOT;
        #pragma unroll
        for (int r=0;r<4;++r){
            float x = tv ? frag[i][r]*scale : -1e30f;
            frag[i][r] = x;
            mx[r] = fmaxf(mx[r], x);
        }
    }
    #pragma unroll
    for (int off=1; off<16; off<<=1)
        #pragma unroll
        for (int r=0;r<4;++r) mx[r] = fmaxf(mx[r], __shfl_xor(mx[r], off));
    if (lc == 0){ redbuf[wave][quad*4+0]=mx[0]; redbuf[wave][quad*4+1]=mx[1];
                  redbuf[wave][quad*4+2]=mx[2]; redbuf[wave][quad*4+3]=mx[3]; }
    __syncthreads();
    float M4[4], sm[4] = {0.f,0.f,0.f,0.f};
    #pragma unroll
    for (int r=0;r<4;++r){
        int rr = quad*4+r;
        M4[r] = fmaxf(fmaxf(redbuf[0][rr], redbuf[1][rr]), fmaxf(redbuf[2][rr], redbuf[3][rr]));
    }
    #pragma unroll
    for (int i=0;i<13;++i)
        #pragma unroll
        for (int r=0;r<4;++r){
            float e = exp2f((frag[i][r] - M4[r]) * 1.44269504f);
            frag[i][r] = e; sm[r] += e;
        }
    #pragma unroll
    for (int off=1; off<16; off<<=1)
        #pragma unroll
        for (int r=0;r<4;++r) sm[r] += __shfl_xor(sm[r], off);
    __syncthreads();
    if (lc == 0){ redbuf[wave][quad*4+0]=sm[0]; redbuf[wave][quad*4+1]=sm[1];
                  redbuf[wave][quad*4+2]=sm[2]; redbuf[wave][quad*4+3]=sm[3]; }
    __syncthreads();
    float inv[4];
    #pragma unroll
    for (int r=0;r<4;++r){
        int rr = quad*4+r;
        inv[r] = 1.0f / (redbuf[0][rr]+redbuf[1][rr]+redbuf[2][rr]+redbuf[3][rr]);
    }
    #pragma unroll
    for (int i=0;i<13;++i){
        int tloc = (i*4+wave)*16 + lc;
        #pragma unroll
        for (int r=0;r<4;++r){
            float p = frag[i][r] * inv[r];
            int srow = quad*4 + r;
            P_lds[srow][tloc] = f2bf(p);
            int sgr = s0 + srow;
            if (sgr < S_TOT && tloc < S_TOT)
                outP[32 + (((long)b*S_TOT + sgr)*8 + h)*S_TOT + tloc] = p;
        }
    }
    __syncthreads();
    // PV: waves (0,2) -> j 0..15, (1,3) -> j 16..31; k-chunks split even/odd
    int jt = wave & 1;
    v4f dacc = (v4f){0.f,0.f,0.f,0.f};
    #pragma unroll
    for (int i=0;i<13;++i){
        int ch = (wave>>1) + 2*i;
        v8s ap = *(const v8s*)&P_lds[lc][ch*32 + quad*8];
        v8s bv;
        #pragma unroll
        for (int j=0;j<8;++j){
            int t = ch*32 + quad*8 + j;
            float vv = (t < S_TOT) ? qkvf[((long)(b*S_TOT + t))*768 + 512 + h*32 + jt*16 + lc] : 0.f;
            bv[j] = (short)f2bf(vv);
        }
        dacc = mfma16(ap, bv, dacc);
    }
    #pragma unroll
    for (int r=0;r<4;++r) attnbuf[wave][quad*4+r][lc] = dacc[r];
    __syncthreads();
    for (int idx = tid; idx < 512; idx += 256){
        int sr = idx >> 5, j = idx & 31;
        float v = attnbuf[j>>4][sr][j&15] + attnbuf[2+(j>>4)][sr][j&15];
        v = fmaxf(v, 0.f);
        if (s0 + sr < S_TOT)
            attn_cat[((long)(b*S_TOT + s0 + sr))*256 + h*32 + j] = f2bf(v);
    }
}

// ---------------- head: partial row-sums then standardize + fc3 + softmax ----------------
__global__ void rowsum_partial(const float* __restrict__ h2, float* __restrict__ part)
{
    int b = blockIdx.x, cch = blockIdx.y, i = threadIdx.x;
    if (i >= 100) return;
    int sBeg = cch*104, sEnd = min(S_TOT, sBeg+104);
    float acc = 0.f;
    for (int s = sBeg; s < sEnd; ++s) acc += h2[((long)b*S_TOT + s)*100 + i];
    part[(b*8 + cch)*100 + i] = acc;
}

__global__ __launch_bounds__(256) void final_head(
    const float* __restrict__ part, const float* __restrict__ fc3w,
    const float* __restrict__ fc3b, float* __restrict__ outp)
{
    __shared__ float r_lds[1600];
    __shared__ float wred[2][4];
    int tid = threadIdx.x;
    float lsum = 0.f, lsq = 0.f;
    for (int idx = tid; idx < 1600; idx += 256){
        int b = idx/100, i = idx%100;
        float s = 0.f;
        for (int c=0;c<8;++c) s += part[(b*8+c)*100 + i];
        r_lds[idx] = s;
        lsum += s; lsq += s*s;
    }
    #pragma unroll
    for (int off=32; off>=1; off>>=1){
        lsum += __shfl_xor(lsum, off);
        lsq  += __shfl_xor(lsq, off);
    }
    int wave = tid >> 6;
    if ((tid & 63) == 0){ wred[0][wave] = lsum; wred[1][wave] = lsq; }
    __syncthreads();
    float S1 = wred[0][0]+wred[0][1]+wred[0][2]+wred[0][3];
    float S2 = wred[1][0]+wred[1][1]+wred[1][2]+wred[1][3];
    float mean = S1/1600.0f;
    float var = (S2 - S1*mean)/1599.0f;   // ddof=1
    float isd = rsqrtf(var);
    if (tid < 16){
        float l0 = fc3b[0], l1 = fc3b[1];
        for (int i=0;i<100;++i){
            float rn = (r_lds[tid*100+i] - mean)*isd;
            l0 += rn * fc3w[i*2+0];
            l1 += rn * fc3w[i*2+1];
        }
        float m = fmaxf(l0, l1);
        float e0 = exp2f((l0-m)*1.44269504f), e1 = exp2f((l1-m)*1.44269504f);
        float d = e0 + e1;
        outp[tid*2+0] = e0/d;
        outp[tid*2+1] = e1/d;
    }
}

extern "C" void kernel_launch(void* const* d_in, const int* in_sizes, int n_in,
                              void* d_out, int out_size, void* d_ws, size_t ws_size,
                              hipStream_t stream)
{
    const float* input_p = (const float*)d_in[0];
    const float* input_e = (const float*)d_in[1];
    const float* conv_p_w = (const float*)d_in[2];
    const float* bn_p_g = (const float*)d_in[3];
    const float* bn_p_b = (const float*)d_in[4];
    const float* bn_p_m = (const float*)d_in[5];
    const float* bn_p_v = (const float*)d_in[6];
    const float* conv_e_w = (const float*)d_in[7];
    const float* bn_e_g = (const float*)d_in[8];
    const float* bn_e_b = (const float*)d_in[9];
    const float* bn_e_m = (const float*)d_in[10];
    const float* bn_e_v = (const float*)d_in[11];
    const float* lstm_w_ih = (const float*)d_in[12];
    const float* lstm_w_hh = (const float*)d_in[13];
    const float* lstm_b_ih = (const float*)d_in[14];
    const float* lstm_b_hh = (const float*)d_in[15];
    const float* wq = (const float*)d_in[16];
    const float* bq = (const float*)d_in[17];
    const float* wk = (const float*)d_in[18];
    const float* bk = (const float*)d_in[19];
    const float* wv = (const float*)d_in[20];
    const float* bv = (const float*)d_in[21];
    const float* mh_w = (const float*)d_in[22];
    const float* mh_b = (const float*)d_in[23];
    const float* fc3_w = (const float*)d_in[24];
    const float* fc3_b = (const float*)d_in[25];
    float* out = (float*)d_out;

    char* ws = (char*)d_ws;
    size_t off = 0;
    auto alloc = [&](size_t bytes)->char*{
        char* p = ws + off; off += (bytes + 255) & ~(size_t)255; return p;
    };
    unsigned short* Xbf   = (unsigned short*)alloc((size_t)MROWS*200*2);
    float*          gatex = (float*)alloc((size_t)2*MROWS*400*4);   // reused as QKV f32
    unsigned short* H0bf  = (unsigned short*)alloc((size_t)MROWS*200*2);
    unsigned short* OUTbf = (unsigned short*)alloc((size_t)MROWS*200*2);
    unsigned short* QKVbf = (unsigned short*)alloc((size_t)MROWS*768*2);
    unsigned short* attnc = (unsigned short*)alloc((size_t)MROWS*256*2);
    float*          h2    = (float*)alloc((size_t)MROWS*100*4);
    float*          part  = (float*)alloc((size_t)16*8*100*4);
    unsigned short* WihBf = (unsigned short*)alloc(320000*2);
    float*          bias2 = (float*)alloc(3200*4);
    unsigned short* WhhBf = (unsigned short*)alloc(160000*2);
    unsigned short* wqkvT = (unsigned short*)alloc(153600*2);
    float*          qkvBias = (float*)alloc(768*4);
    unsigned short* mhwT  = (unsigned short*)alloc(25600*2);
    (void)ws_size; (void)in_sizes; (void)n_in; (void)out_size;

    prep<<<(663168+255)/256, 256, 0, stream>>>(lstm_w_ih, lstm_w_hh, lstm_b_ih, lstm_b_hh,
        wq, bq, wk, bk, wv, bv, mh_w, WihBf, bias2, WhhBf, wqkvT, qkvBias, mhwT);

    conv_pool<<<dim3(PTILES+ETILES, BATCH), 256, 0, stream>>>(input_p, input_e,
        conv_p_w, bn_p_g, bn_p_b, bn_p_m, bn_p_v,
        conv_e_w, bn_e_g, bn_e_b, bn_e_m, bn_e_v, Xbf);

    // layer 0: gate_x GEMM (both dirs), then scan
    dim3 gGate((MROWS+63)/64, (400+63)/64, 2);
    gemm_bf16<<<gGate, 256, 0, stream>>>(Xbf, WihBf, bias2, gatex, nullptr,
        MROWS, 400, 200, (long)400*200, 400, (long)MROWS*400, 0);
    lstm_scan<<<16, 512, 0, stream>>>(gatex, WhhBf, H0bf);

    // layer 1
    gemm_bf16<<<gGate, 256, 0, stream>>>(H0bf, WihBf + 2*400*200, bias2 + 800, gatex, nullptr,
        MROWS, 400, 200, (long)400*200, 400, (long)MROWS*400, 0);
    lstm_scan<<<16, 512, 0, stream>>>(gatex, WhhBf + 2*400*100, OUTbf);

    // QKV projection (fp32 + bf16 outputs); fp32 aliases gatex (dead now)
    float* QKVf = gatex;
    dim3 gQKV((MROWS+63)/64, 768/64, 1);
    gemm_bf16<<<gQKV, 256, 0, stream>>>(OUTbf, wqkvT, qkvBias, QKVf, QKVbf,
        MROWS, 768, 200, 0, 0, 0, 0);

    // fused attention: scores -> softmax (into d_out) -> PV -> attn_cat bf16
    dim3 gAttn(52, 128);
    attn_fused<<<gAttn, 256, 0, stream>>>(QKVbf, QKVf, out, attnc);

    // mh dense + relu
    dim3 gMh((MROWS+63)/64, (100+63)/64, 1);
    gemm_bf16<<<gMh, 256, 0, stream>>>(attnc, mhwT, mh_b, h2, nullptr,
        MROWS, 100, 256, 0, 0, 0, 1);

    rowsum_partial<<<dim3(16,8), 128, 0, stream>>>(h2, part);
    final_head<<<1, 256, 0, stream>>>(part, fc3_w, fc3_b, out);
}